// Round 4
// baseline (787.249 us; speedup 1.0000x reference)
//
#include <hip/hip_runtime.h>
#include <cmath>
#include <cstdint>
#include <cstddef>

typedef unsigned long long u64;
typedef unsigned int u32;

#define NPX   2500
#define NANCH 22500
#define PRE_TOPK 10000
#define NWORDS 160      // 160*64 = 10240 bits per NMS row

struct AnchorBase { float b[36]; };

typedef __attribute__((ext_vector_type(8))) short bf16x8;
typedef __attribute__((ext_vector_type(4))) float f32x4;

__device__ inline unsigned short f2bf(float f) {
    u32 u = __float_as_uint(f);
    u32 r = u + 0x7fffu + ((u >> 16) & 1u);
    return (unsigned short)(r >> 16);
}
__device__ inline float bf2f(unsigned short h) {
    return __uint_as_float(((u32)h) << 16);
}

// ---------------------------------------------------------------------------
// KPREP: fused input prep.
//  blocks [0,416):  feat [c][px] -> Xt[cell][c] bf16 hi/lo on zero-padded
//                   52x64 grid (pad cells written as zero -> no memset).
//  blocks [416,928): wr [oc][c][tap] -> W'[oc][tap*512+c] bf16 hi/lo.
// ---------------------------------------------------------------------------
__global__ __launch_bounds__(256) void kprep(const float* __restrict__ feat,
                                             const float* __restrict__ wr,
                                             unsigned short* __restrict__ xthi,
                                             unsigned short* __restrict__ xtlo,
                                             unsigned short* __restrict__ whi,
                                             unsigned short* __restrict__ wlo)
{
    __shared__ float sh[4608];
    int bid = blockIdx.x;
    int t = threadIdx.x;
    if (bid < 416) {
        float (*tile)[65] = (float(*)[65])sh;
        int gr = bid >> 3;          // grid row 0..51
        int cc = bid & 7;           // c-chunk
        int tx = t & 63, ty = t >> 6;
        int y = gr - 1;
        bool rowok = (gr >= 1) && (gr <= 50);
#pragma unroll
        for (int i = 0; i < 16; ++i) {
            int c = i * 4 + ty;
            tile[c][tx] = (rowok && tx < 50)
                        ? feat[(size_t)(cc * 64 + c) * NPX + y * 50 + tx] : 0.f;
        }
        __syncthreads();
#pragma unroll
        for (int i = 0; i < 16; ++i) {
            int xp = i * 4 + ty;
            int cell = gr * 64 + xp;
            bool ok = rowok && xp >= 1 && xp <= 50;
            float v = ok ? tile[tx][xp - 1] : 0.f;
            unsigned short hi = f2bf(v);
            xthi[(size_t)cell * 512 + cc * 64 + tx] = hi;
            xtlo[(size_t)cell * 512 + cc * 64 + tx] = f2bf(v - bf2f(hi));
        }
    } else {
        int oc = bid - 416;         // 0..511
        for (int j = t; j < 4608; j += 256) sh[j] = wr[(size_t)oc * 4608 + j];
        __syncthreads();
        for (int k = t; k < 4608; k += 256) {
            int c = k & 511, tap = k >> 9;
            float v = sh[c * 9 + tap];
            unsigned short hi = f2bf(v);
            whi[(size_t)oc * 4608 + k] = hi;
            wlo[(size_t)oc * 4608 + k] = f2bf(v - bf2f(hi));
        }
    }
}

// ---------------------------------------------------------------------------
// K1m v3: conv as bf16x3 MFMA GEMM, c-split K partitioning (L2-friendly:
// block working set ~0.5 MB), depth-1 software-pipelined frag prefetch.
// Wave = 32oc x 64px. Block = 64oc x 128px. Grid (20, 8, ns).
// ---------------------------------------------------------------------------
struct Frag {
    bf16x8 ah0, ah1, al0, al1;
    bf16x8 bh0, bh1, bh2, bh3, bl0, bl1, bl2, bl3;
};

__device__ inline void k1_load(Frag& F, int it, int cperm1, int cperLog, int chb,
                               int quad, int p0, int p1, int p2, int p3,
                               size_t wrow0, size_t wrow1,
                               const unsigned short* __restrict__ xthi,
                               const unsigned short* __restrict__ xtlo,
                               const unsigned short* __restrict__ whi,
                               const unsigned short* __restrict__ wlo)
{
    int tap = it >> cperLog;
    int cw  = it & cperm1;
    int kq  = (chb + cw) * 32 + quad * 8;
    int kw  = tap * 512 + kq;
    int t3  = (tap * 43) >> 7;             // tap/3
    int tapoff = (t3 - 1) * 64 + (tap - t3 * 3) - 1;
    F.ah0 = *(const bf16x8*)(whi + wrow0 + kw);
    F.ah1 = *(const bf16x8*)(whi + wrow1 + kw);
    F.al0 = *(const bf16x8*)(wlo + wrow0 + kw);
    F.al1 = *(const bf16x8*)(wlo + wrow1 + kw);
    size_t o0 = (size_t)(p0 + tapoff) * 512 + kq;
    size_t o1 = (size_t)(p1 + tapoff) * 512 + kq;
    size_t o2 = (size_t)(p2 + tapoff) * 512 + kq;
    size_t o3 = (size_t)(p3 + tapoff) * 512 + kq;
    F.bh0 = *(const bf16x8*)(xthi + o0);
    F.bh1 = *(const bf16x8*)(xthi + o1);
    F.bh2 = *(const bf16x8*)(xthi + o2);
    F.bh3 = *(const bf16x8*)(xthi + o3);
    F.bl0 = *(const bf16x8*)(xtlo + o0);
    F.bl1 = *(const bf16x8*)(xtlo + o1);
    F.bl2 = *(const bf16x8*)(xtlo + o2);
    F.bl3 = *(const bf16x8*)(xtlo + o3);
}

__device__ inline void k1_step(const Frag& F, f32x4* a)
{
#define MF(d, A, B) d = __builtin_amdgcn_mfma_f32_16x16x32_bf16(F.A, F.B, d, 0, 0, 0)
    MF(a[0], al0, bh0); MF(a[0], ah0, bl0); MF(a[0], ah0, bh0);
    MF(a[1], al0, bh1); MF(a[1], ah0, bl1); MF(a[1], ah0, bh1);
    MF(a[2], al0, bh2); MF(a[2], ah0, bl2); MF(a[2], ah0, bh2);
    MF(a[3], al0, bh3); MF(a[3], ah0, bl3); MF(a[3], ah0, bh3);
    MF(a[4], al1, bh0); MF(a[4], ah1, bl0); MF(a[4], ah1, bh0);
    MF(a[5], al1, bh1); MF(a[5], ah1, bl1); MF(a[5], ah1, bh1);
    MF(a[6], al1, bh2); MF(a[6], ah1, bl2); MF(a[6], ah1, bh2);
    MF(a[7], al1, bh3); MF(a[7], ah1, bl3); MF(a[7], ah1, bh3);
#undef MF
}

__global__ __launch_bounds__(256) void k1m(const unsigned short* __restrict__ xthi,
                                           const unsigned short* __restrict__ xtlo,
                                           const unsigned short* __restrict__ whi,
                                           const unsigned short* __restrict__ wlo,
                                           float* __restrict__ pk,
                                           int cper, int cperLog)
{
    int t = threadIdx.x;
    int lane = t & 63, wave = t >> 6;
    int wo = wave & 1, wp = wave >> 1;
    int pb = blockIdx.x, ob = blockIdx.y, bs = blockIdx.z;
    int quad = lane >> 4, m = lane & 15;
    int ocbase = ob * 64 + wo * 32;
    int pxbase = pb * 128 + wp * 64;
    int chb = bs * cper;
    int cperm1 = cper - 1;

    int prow[4];
#pragma unroll
    for (int sp = 0; sp < 4; ++sp) {
        int opx = pxbase + sp * 16 + m;
        prow[sp] = (opx < NPX) ? ((opx / 50) + 1) * 64 + (opx % 50) + 1 : 190;
    }
    size_t wrow0 = (size_t)(ocbase + m) * 4608;
    size_t wrow1 = wrow0 + (size_t)16 * 4608;

    f32x4 acc[8];
    f32x4 zf = {0.f, 0.f, 0.f, 0.f};
#pragma unroll
    for (int i = 0; i < 8; ++i) acc[i] = zf;

    int niter = 9 * cper;   // 18 / 36 / 72, always even
    Frag F0, F1;
    k1_load(F0, 0, cperm1, cperLog, chb, quad, prow[0], prow[1], prow[2], prow[3],
            wrow0, wrow1, xthi, xtlo, whi, wlo);
    for (int it = 0; it < niter; it += 2) {
        k1_load(F1, it + 1, cperm1, cperLog, chb, quad, prow[0], prow[1], prow[2], prow[3],
                wrow0, wrow1, xthi, xtlo, whi, wlo);
        k1_step(F0, acc);
        if (it + 2 < niter)
            k1_load(F0, it + 2, cperm1, cperLog, chb, quad, prow[0], prow[1], prow[2], prow[3],
                    wrow0, wrow1, xthi, xtlo, whi, wlo);
        k1_step(F1, acc);
    }
    // C/D: col(px)=lane&15, row(oc)=quad*4+reg
#pragma unroll
    for (int so = 0; so < 2; ++so)
#pragma unroll
        for (int sp = 0; sp < 4; ++sp)
#pragma unroll
            for (int r = 0; r < 4; ++r) {
                int oc = ocbase + so * 16 + quad * 4 + r;
                int px = pxbase + sp * 16 + m;
                pk[((size_t)bs * 512 + oc) * 2560 + px] = acc[so * 4 + sp][r];
            }
}

// ---------------------------------------------------------------------------
// K2: fused k-split reduce + bias + ReLU + 1x1 heads + sigmoid + box decode.
// One block per 64-px tile. Per 64-c chunk: stage v=relu(sum pk + br) and the
// 45x64 weight tile in LDS, accumulate 45 head outputs; then decode 576
// anchors of the tile.
// ---------------------------------------------------------------------------
__global__ __launch_bounds__(256) void k2_heads(const float* __restrict__ pk, int ns,
                                                const float* __restrict__ br,
                                                const float* __restrict__ wcls,
                                                const float* __restrict__ bcls,
                                                const float* __restrict__ wreg,
                                                const float* __restrict__ breg,
                                                AnchorBase ab,
                                                float* __restrict__ score,
                                                float* __restrict__ bx1, float* __restrict__ by1,
                                                float* __restrict__ bx2, float* __restrict__ by2,
                                                u32* __restrict__ valid,
                                                u64* __restrict__ key)
{
    __shared__ float sh[4096 + 3072];   // vt[64][64] + Wl[48][64] (padded)
    float* vt = sh;
    float* Wl = sh + 4096;
    int t = threadIdx.x;
    int pb = blockIdx.x;
    int pxl = t & 63, ug = t >> 6;
    int ubase = ug * 12;
    int ulim = (45 - ubase < 12) ? (45 - ubase) : 12;
    int px = pb * 64 + pxl;

    float acc[12];
#pragma unroll
    for (int j = 0; j < 12; ++j)
        acc[j] = (j < ulim) ? ((ubase + j < 9) ? bcls[ubase + j] : breg[ubase + j - 9]) : 0.f;

    for (int cc = 0; cc < 8; ++cc) {
        int cb = cc * 64;
        for (int e = t; e < 2880; e += 256) {
            int u = e >> 6, c = e & 63;
            Wl[e] = (u < 9) ? wcls[u * 512 + cb + c] : wreg[(u - 9) * 512 + cb + c];
        }
#pragma unroll
        for (int i = 0; i < 16; ++i) {
            int cl = i * 4 + ug;
            float v = 0.f;
            if (px < NPX) {
                size_t bidx = (size_t)(cb + cl) * 2560 + px;
                v = br[cb + cl];
                for (int s = 0; s < ns; ++s) v += pk[(size_t)s * 512 * 2560 + bidx];
                v = v > 0.f ? v : 0.f;
            }
            vt[cl * 64 + pxl] = v;
        }
        __syncthreads();
        for (int c = 0; c < 64; ++c) {
            float v = vt[c * 64 + pxl];
#pragma unroll
            for (int j = 0; j < 12; ++j)
                acc[j] = fmaf(v, Wl[(ubase + j) * 64 + c], acc[j]);
        }
        __syncthreads();
    }
    for (int j = 0; j < ulim; ++j) sh[(ubase + j) * 64 + pxl] = acc[j];
    __syncthreads();

    for (int a = t; a < 576; a += 256) {
        int pl = a / 9;
        int k  = a - pl * 9;
        int gpx = pb * 64 + pl;
        if (gpx >= NPX) continue;
        float z  = sh[k * 64 + pl];
        float d0 = sh[(9 + k * 4 + 0) * 64 + pl];
        float d1 = sh[(9 + k * 4 + 1) * 64 + pl];
        float d2 = sh[(9 + k * 4 + 2) * 64 + pl];
        float d3 = sh[(9 + k * 4 + 3) * 64 + pl];
        float sc = 1.f / (1.f + expf(-z));

        int yy = gpx / 50, xx = gpx - yy * 50;
        float fx = (float)xx, fy = (float)yy;
        float ax1 = fx + ab.b[k * 4 + 0], ay1 = fy + ab.b[k * 4 + 1];
        float ax2 = fx + ab.b[k * 4 + 2], ay2 = fy + ab.b[k * 4 + 3];
        float aw = ax2 - ax1, ah = ay2 - ay1;
        float cx = ax1 + 0.5f * aw, cy = ay1 + 0.5f * ah;
        float pcx = d0 * aw + cx, pcy = d1 * ah + cy;
        float pw = expf(d2) * aw, ph = expf(d3) * ah;
        float x1 = pcx - 0.5f * pw, y1 = pcy - 0.5f * ph;
        float x2 = pcx + 0.5f * pw, y2 = pcy + 0.5f * ph;
        x1 = fminf(fmaxf(x1, 0.f), 800.f);
        y1 = fminf(fmaxf(y1, 0.f), 800.f);
        x2 = fminf(fmaxf(x2, 0.f), 800.f);
        y2 = fminf(fmaxf(y2, 0.f), 800.f);
        u32 v = ((x2 - x1) >= 16.f) && ((y2 - y1) >= 16.f);

        int f = gpx * 9 + k;
        score[f] = sc;
        bx1[f] = x1; by1[f] = y1; bx2[f] = x2; by2[f] = y2;
        valid[f] = v;
        u32 sb = __float_as_uint(sc);
        key[f] = ((u64)(~sb) << 32) | (u32)f;
    }
}

// ---------------------------------------------------------------------------
// K3a: partial ranks (deterministic, no atomics). rankp[jb][i] = count in chunk.
// ---------------------------------------------------------------------------
__global__ __launch_bounds__(256) void k3a_rank(const u64* __restrict__ key,
                                                u32* __restrict__ rankp)
{
    __shared__ u64 sk[4500];
    int t  = threadIdx.x;
    int jb = blockIdx.y;
    for (int e = t; e < 4500; e += 256) sk[e] = key[jb * 4500 + e];
    __syncthreads();
    int i = blockIdx.x * 256 + t;
    if (i >= NANCH) return;
    u64 ki = key[i];
    u32 cnt = 0;
#pragma unroll 8
    for (int j = 0; j < 4500; ++j) cnt += (sk[j] < ki) ? 1u : 0u;
    rankp[(size_t)jb * NANCH + i] = cnt;
}

// ---------------------------------------------------------------------------
// K3b: sum partial ranks, scatter top-10000; sInv[r] = 1 if invalid box.
// ---------------------------------------------------------------------------
__global__ __launch_bounds__(256) void k3b_gather(const u32* __restrict__ rankp,
                                                  const float* __restrict__ score,
                                                  const float* __restrict__ bx1, const float* __restrict__ by1,
                                                  const float* __restrict__ bx2, const float* __restrict__ by2,
                                                  const u32* __restrict__ valid,
                                                  float* __restrict__ sS,
                                                  float* __restrict__ sx1, float* __restrict__ sy1,
                                                  float* __restrict__ sx2, float* __restrict__ sy2,
                                                  float* __restrict__ sA,
                                                  u32* __restrict__ sInv)
{
    int i = blockIdx.x * 256 + threadIdx.x;
    if (i >= NANCH) return;
    u32 r = rankp[i] + rankp[NANCH + i] + rankp[2 * NANCH + i]
          + rankp[3 * NANCH + i] + rankp[4 * NANCH + i];
    if (r >= PRE_TOPK) return;
    float x1 = bx1[i], y1 = by1[i], x2 = bx2[i], y2 = by2[i];
    sS[r] = score[i];
    sx1[r] = x1; sy1[r] = y1; sx2[r] = x2; sy2[r] = y2;
    sA[r] = (x2 - x1) * (y2 - y1);
    sInv[r] = valid[i] ? 0u : 1u;
}

// ---------------------------------------------------------------------------
// K4: pairwise suppression matrix + selfw[i] = rows[i][i>>6].
// ---------------------------------------------------------------------------
__global__ __launch_bounds__(256) void k4_mat(const float* __restrict__ sx1, const float* __restrict__ sy1,
                                              const float* __restrict__ sx2, const float* __restrict__ sy2,
                                              const float* __restrict__ sA,
                                              u64* __restrict__ rows,
                                              u64* __restrict__ selfw)
{
    __shared__ float jx1[1024], jy1[1024], jx2[1024], jy2[1024], ja[1024];
    int t  = threadIdx.x;
    int ib = blockIdx.x;
    int jc = blockIdx.y;
    for (int e = t; e < 1024; e += 256) {
        int j = jc * 1024 + e;
        bool okj = j < PRE_TOPK;
        jx1[e] = okj ? sx1[j] : 0.f;
        jy1[e] = okj ? sy1[j] : 0.f;
        jx2[e] = okj ? sx2[j] : 0.f;
        jy2[e] = okj ? sy2[j] : 0.f;
        ja[e]  = okj ? sA[j]  : 0.f;
    }
    __syncthreads();
    int i = ib * 256 + t;
    if (i >= PRE_TOPK) return;
    u64* rowp = rows + (size_t)i * NWORDS + jc * 16;
    if (jc * 1024 + 1023 <= i) {
#pragma unroll
        for (int w = 0; w < 16; ++w) rowp[w] = 0ull;
        int sw_ = i >> 6;
        if (sw_ >= jc * 16 && sw_ < jc * 16 + 16) selfw[i] = 0ull;
        return;
    }
    float x1 = sx1[i], y1 = sy1[i], x2 = sx2[i], y2 = sy2[i], ai = sA[i];
    u64 word = 0;
#pragma unroll 4
    for (int e = 0; e < 1024; ++e) {
        int j = jc * 1024 + e;
        float xx1 = fmaxf(x1, jx1[e]);
        float yy1 = fmaxf(y1, jy1[e]);
        float xx2 = fminf(x2, jx2[e]);
        float yy2 = fminf(y2, jy2[e]);
        float iw = fmaxf(xx2 - xx1, 0.f);
        float ih = fmaxf(yy2 - yy1, 0.f);
        float inter = iw * ih;
        float uni = ai + ja[e] - inter;
        bool sup = (inter > 0.7f * uni) && (j > i) && (j < PRE_TOPK);
        word |= ((u64)sup) << (e & 63);
        if ((e & 63) == 63) {
            rowp[e >> 6] = word;
            if ((jc * 16 + (e >> 6)) == (i >> 6)) selfw[i] = word;
            word = 0;
        }
    }
}

// ---------------------------------------------------------------------------
// K5: word-batched greedy NMS scan; builds initial removed bits from sInv,
// zero-fills all 2000 output slots (no out memset needed).
// ---------------------------------------------------------------------------
__global__ __launch_bounds__(64) void k5_scan(const u64* __restrict__ rows,
                                              const u64* __restrict__ selfw,
                                              const u32* __restrict__ sInv,
                                              const float* __restrict__ sS,
                                              const float* __restrict__ sx1, const float* __restrict__ sy1,
                                              const float* __restrict__ sx2, const float* __restrict__ sy2,
                                              float* __restrict__ out)
{
    __shared__ int keptList[2000];
    __shared__ int kcnt;
    int l = threadIdx.x;
    auto bw = [&](int w) -> u64 {
        const uint4* p = (const uint4*)(sInv + (size_t)w * 64);
        u64 v = 0;
#pragma unroll
        for (int j = 0; j < 16; ++j) {
            uint4 q = p[j];
            v |= ((u64)(q.x != 0) << (j * 4))     | ((u64)(q.y != 0) << (j * 4 + 1))
               | ((u64)(q.z != 0) << (j * 4 + 2)) | ((u64)(q.w != 0) << (j * 4 + 3));
        }
        return v;
    };
    u64 r0 = bw(l);
    u64 r1 = bw(64 + l);
    u64 r2 = (l < 32) ? bw(128 + l) : ~0ull;
    u64 swreg = selfw[l];
    int cnt = 0;
    bool done = false;
    for (int w = 0; w < 157 && !done; ++w) {
        u64 swnext = (w < 156) ? selfw[(size_t)(w + 1) * 64 + l] : 0ull;
        int slot = w >> 6, owner = w & 63;
        u64 val = (slot == 0) ? r0 : (slot == 1) ? r1 : r2;
        u64 rw = __shfl(val, owner, 64);
        u64 wmask = (w == 156) ? 0xFFFFull : ~0ull;
        u64 av = (~rw) & wmask;
        u64 km = 0;
        while (av) {                     // intra-word resolve, registers only
            int b = __ffsll((unsigned long long)av) - 1;
            u64 sw = __shfl(swreg, b, 64);
            km |= 1ull << b;
            av &= ~(1ull << b);
            av &= ~sw;
        }
        u64 kk = km;
        while (kk) {                     // OR kept rows, 8 per batch
            int bsx[8];
            int nb = 0;
            while (kk && nb < 8) {
                int b = __ffsll((unsigned long long)kk) - 1;
                kk &= kk - 1;
                bsx[nb++] = b;
            }
            u64 a0 = 0, a1 = 0, a2 = 0;
#pragma unroll
            for (int u = 0; u < 8; ++u) {
                if (u < nb) {
                    int i = (w << 6) + bsx[u];
                    if (l == 0 && cnt + u < 2000) keptList[cnt + u] = i;
                    const u64* rp = rows + (size_t)i * NWORDS;
                    a0 |= rp[l];
                    a1 |= rp[64 + l];
                    if (l < 32) a2 |= rp[128 + l];
                }
            }
            r0 |= a0; r1 |= a1; r2 |= a2;
            cnt += nb;
            if (cnt >= 2000) { done = true; break; }
        }
        swreg = swnext;
    }
    if (l == 0) kcnt = (cnt < 2000) ? cnt : 2000;
    __syncthreads();
    int K = kcnt;
    for (int r = l; r < 2000; r += 64) {
        if (r < K) {
            int j = keptList[r];
            out[r * 4 + 0] = sx1[j];
            out[r * 4 + 1] = sy1[j];
            out[r * 4 + 2] = sx2[j];
            out[r * 4 + 3] = sy2[j];
            out[8000 + r]  = sS[j];
        } else {
            out[r * 4 + 0] = 0.f; out[r * 4 + 1] = 0.f;
            out[r * 4 + 2] = 0.f; out[r * 4 + 3] = 0.f;
            out[8000 + r]  = 0.f;
        }
    }
}

// ---------------------------------------------------------------------------
extern "C" void kernel_launch(void* const* d_in, const int* in_sizes, int n_in,
                              void* d_out, int out_size, void* d_ws, size_t ws_size,
                              hipStream_t stream)
{
    (void)in_sizes; (void)n_in; (void)out_size;
    const float* feat = (const float*)d_in[1];
    const float* wrpn = (const float*)d_in[3];
    const float* brpn = (const float*)d_in[4];
    const float* wcls = (const float*)d_in[5];
    const float* bcls = (const float*)d_in[6];
    const float* wreg = (const float*)d_in[7];
    const float* breg = (const float*)d_in[8];
    float* out = (float*)d_out;

    // K-split factor by workspace budget. need(ns) = ns*512*2560*4 + 16,252,928.
    int ns = (ws_size >= 58195968) ? 8 : (ws_size >= 37224448) ? 4 : 2;
    int cper = 16 / ns;
    int cperLog = (ns == 2) ? 3 : (ns == 4) ? 2 : 1;
    size_t pkB = (size_t)ns * 512 * 2560 * 4;

    char* ws = (char*)d_ws;
    // [0, pkB): pk, live k1m..k2.
    // [pkB, pkB+16.25M): Xt hi/lo + W hi/lo, live kprep..k1m; after k1m this
    // region is reused for the small arrays (written k2+) and rows (k4+).
    float* pk = (float*)ws;
    unsigned short* Xthi = (unsigned short*)(ws + pkB);
    unsigned short* Xtlo = Xthi + (size_t)52 * 64 * 512;
    unsigned short* Whi  = (unsigned short*)(ws + pkB + 6815744);
    unsigned short* Wlo  = Whi + (size_t)512 * 4608;

    char* sm = ws + pkB;                         // overlays Xt/W (dead after k1m)
    float* score = (float*)(sm + 0);             // 90,000
    float* bx1   = (float*)(sm + 90000);
    float* by1   = (float*)(sm + 180000);
    float* bx2   = (float*)(sm + 270000);
    float* by2   = (float*)(sm + 360000);
    u32*   valid = (u32*)  (sm + 450000);
    u64*   key   = (u64*)  (sm + 540000);        // 180,000
    u32*   rankp = (u32*)  (sm + 720000);        // 450,000
    float* sS    = (float*)(sm + 1170000);
    float* sx1   = (float*)(sm + 1210000);
    float* sy1   = (float*)(sm + 1250000);
    float* sx2   = (float*)(sm + 1290000);
    float* sy2   = (float*)(sm + 1330000);
    float* sA    = (float*)(sm + 1370000);
    u32*   sInv  = (u32*)  (sm + 1410000);       // 40,960 (10240 u32, tail unused)
    u64*   selfw = (u64*)  (sm + 1450960);       // 81,920
    u64*   rows  = (u64*)  (sm + 1532880);       // 12,800,000 -> ends sm+14.33M < sm+16.25M
    // peak footprint = pkB + 16,252,928 bytes (ns=4 -> 37.2 MB, ns=8 -> 58.2 MB)

    AnchorBase ab;
    {
        const float scales[3] = {128.f, 256.f, 512.f};
        const float aspect[3] = {0.5f, 1.f, 2.f};
        for (int ai = 0; ai < 3; ++ai) {
            float hr = sqrtf(aspect[ai]);
            float wratio = 1.0f / hr;
            for (int si = 0; si < 3; ++si) {
                float wsz = wratio * scales[si];
                float hsz = hr * scales[si];
                int a = ai * 3 + si;
                ab.b[a * 4 + 0] = rintf(-wsz / 2.0f);
                ab.b[a * 4 + 1] = rintf(-hsz / 2.0f);
                ab.b[a * 4 + 2] = rintf( wsz / 2.0f);
                ab.b[a * 4 + 3] = rintf( hsz / 2.0f);
            }
        }
    }

    kprep    <<<928, 256, 0, stream>>>(feat, wrpn, Xthi, Xtlo, Whi, Wlo);
    k1m      <<<dim3(20, 8, ns), 256, 0, stream>>>(Xthi, Xtlo, Whi, Wlo, pk, cper, cperLog);
    k2_heads <<<40, 256, 0, stream>>>(pk, ns, brpn, wcls, bcls, wreg, breg, ab,
                                      score, bx1, by1, bx2, by2, valid, key);
    k3a_rank <<<dim3(88, 5), 256, 0, stream>>>(key, rankp);
    k3b_gather<<<88, 256, 0, stream>>>(rankp, score, bx1, by1, bx2, by2, valid,
                                       sS, sx1, sy1, sx2, sy2, sA, sInv);
    k4_mat   <<<dim3(40, 10), 256, 0, stream>>>(sx1, sy1, sx2, sy2, sA, rows, selfw);
    k5_scan  <<<1, 64, 0, stream>>>(rows, selfw, sInv, sS, sx1, sy1, sx2, sy2, out);
}

// Round 5
// 518.810 us; speedup vs baseline: 1.5174x; 1.5174x over previous
//
#include <hip/hip_runtime.h>
#include <cmath>
#include <cstdint>
#include <cstddef>

typedef unsigned long long u64;
typedef unsigned int u32;

#define NPX   2500
#define NANCH 22500
#define PRE_TOPK 10000
#define NWORDS 160      // 160*64 = 10240 bits per NMS row

struct AnchorBase { float b[36]; };

typedef __attribute__((ext_vector_type(8))) short bf16x8;
typedef __attribute__((ext_vector_type(4))) float f32x4;

__device__ inline unsigned short f2bf(float f) {
    u32 u = __float_as_uint(f);
    u32 r = u + 0x7fffu + ((u >> 16) & 1u);
    return (unsigned short)(r >> 16);
}
__device__ inline float bf2f(unsigned short h) {
    return __uint_as_float(((u32)h) << 16);
}

// ---------------------------------------------------------------------------
// KPREP: fused input prep.
//  blocks [0,416):  feat [c][px] -> Xt[cell][c] bf16 hi/lo on zero-padded
//                   52x64 grid (pad cells written as zero -> no memset).
//  blocks [416,928): wr [oc][c][tap] -> W'[oc][tap*512+c] bf16 hi/lo.
// ---------------------------------------------------------------------------
__global__ __launch_bounds__(256) void kprep(const float* __restrict__ feat,
                                             const float* __restrict__ wr,
                                             unsigned short* __restrict__ xthi,
                                             unsigned short* __restrict__ xtlo,
                                             unsigned short* __restrict__ whi,
                                             unsigned short* __restrict__ wlo)
{
    __shared__ float sh[4608];
    int bid = blockIdx.x;
    int t = threadIdx.x;
    if (bid < 416) {
        float (*tile)[65] = (float(*)[65])sh;
        int gr = bid >> 3;          // grid row 0..51
        int cc = bid & 7;           // c-chunk
        int tx = t & 63, ty = t >> 6;
        int y = gr - 1;
        bool rowok = (gr >= 1) && (gr <= 50);
#pragma unroll
        for (int i = 0; i < 16; ++i) {
            int c = i * 4 + ty;
            tile[c][tx] = (rowok && tx < 50)
                        ? feat[(size_t)(cc * 64 + c) * NPX + y * 50 + tx] : 0.f;
        }
        __syncthreads();
#pragma unroll
        for (int i = 0; i < 16; ++i) {
            int xp = i * 4 + ty;
            int cell = gr * 64 + xp;
            bool ok = rowok && xp >= 1 && xp <= 50;
            float v = ok ? tile[tx][xp - 1] : 0.f;
            unsigned short hi = f2bf(v);
            xthi[(size_t)cell * 512 + cc * 64 + tx] = hi;
            xtlo[(size_t)cell * 512 + cc * 64 + tx] = f2bf(v - bf2f(hi));
        }
    } else {
        int oc = bid - 416;         // 0..511
        for (int j = t; j < 4608; j += 256) sh[j] = wr[(size_t)oc * 4608 + j];
        __syncthreads();
        for (int k = t; k < 4608; k += 256) {
            int c = k & 511, tap = k >> 9;
            float v = sh[c * 9 + tap];
            unsigned short hi = f2bf(v);
            whi[(size_t)oc * 4608 + k] = hi;
            wlo[(size_t)oc * 4608 + k] = f2bf(v - bf2f(hi));
        }
    }
}

// ---------------------------------------------------------------------------
// K1m: conv as bf16x3 MFMA GEMM, c-split K partitioning, depth-1 pipelined.
// Wave = 32oc x 64px. Block = 64oc x 128px. Grid (20, 8, ns).
// ---------------------------------------------------------------------------
struct Frag {
    bf16x8 ah0, ah1, al0, al1;
    bf16x8 bh0, bh1, bh2, bh3, bl0, bl1, bl2, bl3;
};

__device__ inline void k1_load(Frag& F, int it, int cperm1, int cperLog, int chb,
                               int quad, int p0, int p1, int p2, int p3,
                               size_t wrow0, size_t wrow1,
                               const unsigned short* __restrict__ xthi,
                               const unsigned short* __restrict__ xtlo,
                               const unsigned short* __restrict__ whi,
                               const unsigned short* __restrict__ wlo)
{
    int tap = it >> cperLog;
    int cw  = it & cperm1;
    int kq  = (chb + cw) * 32 + quad * 8;
    int kw  = tap * 512 + kq;
    int t3  = (tap * 43) >> 7;             // tap/3
    int tapoff = (t3 - 1) * 64 + (tap - t3 * 3) - 1;
    F.ah0 = *(const bf16x8*)(whi + wrow0 + kw);
    F.ah1 = *(const bf16x8*)(whi + wrow1 + kw);
    F.al0 = *(const bf16x8*)(wlo + wrow0 + kw);
    F.al1 = *(const bf16x8*)(wlo + wrow1 + kw);
    size_t o0 = (size_t)(p0 + tapoff) * 512 + kq;
    size_t o1 = (size_t)(p1 + tapoff) * 512 + kq;
    size_t o2 = (size_t)(p2 + tapoff) * 512 + kq;
    size_t o3 = (size_t)(p3 + tapoff) * 512 + kq;
    F.bh0 = *(const bf16x8*)(xthi + o0);
    F.bh1 = *(const bf16x8*)(xthi + o1);
    F.bh2 = *(const bf16x8*)(xthi + o2);
    F.bh3 = *(const bf16x8*)(xthi + o3);
    F.bl0 = *(const bf16x8*)(xtlo + o0);
    F.bl1 = *(const bf16x8*)(xtlo + o1);
    F.bl2 = *(const bf16x8*)(xtlo + o2);
    F.bl3 = *(const bf16x8*)(xtlo + o3);
}

__device__ inline void k1_step(const Frag& F, f32x4* a)
{
#define MF(d, A, B) d = __builtin_amdgcn_mfma_f32_16x16x32_bf16(F.A, F.B, d, 0, 0, 0)
    MF(a[0], al0, bh0); MF(a[0], ah0, bl0); MF(a[0], ah0, bh0);
    MF(a[1], al0, bh1); MF(a[1], ah0, bl1); MF(a[1], ah0, bh1);
    MF(a[2], al0, bh2); MF(a[2], ah0, bl2); MF(a[2], ah0, bh2);
    MF(a[3], al0, bh3); MF(a[3], ah0, bl3); MF(a[3], ah0, bh3);
    MF(a[4], al1, bh0); MF(a[4], ah1, bl0); MF(a[4], ah1, bh0);
    MF(a[5], al1, bh1); MF(a[5], ah1, bl1); MF(a[5], ah1, bh1);
    MF(a[6], al1, bh2); MF(a[6], ah1, bl2); MF(a[6], ah1, bh2);
    MF(a[7], al1, bh3); MF(a[7], ah1, bl3); MF(a[7], ah1, bh3);
#undef MF
}

__global__ __launch_bounds__(256) void k1m(const unsigned short* __restrict__ xthi,
                                           const unsigned short* __restrict__ xtlo,
                                           const unsigned short* __restrict__ whi,
                                           const unsigned short* __restrict__ wlo,
                                           float* __restrict__ pk,
                                           int cper, int cperLog)
{
    int t = threadIdx.x;
    int lane = t & 63, wave = t >> 6;
    int wo = wave & 1, wp = wave >> 1;
    int pb = blockIdx.x, ob = blockIdx.y, bs = blockIdx.z;
    int quad = lane >> 4, m = lane & 15;
    int ocbase = ob * 64 + wo * 32;
    int pxbase = pb * 128 + wp * 64;
    int chb = bs * cper;
    int cperm1 = cper - 1;

    int prow[4];
#pragma unroll
    for (int sp = 0; sp < 4; ++sp) {
        int opx = pxbase + sp * 16 + m;
        prow[sp] = (opx < NPX) ? ((opx / 50) + 1) * 64 + (opx % 50) + 1 : 190;
    }
    size_t wrow0 = (size_t)(ocbase + m) * 4608;
    size_t wrow1 = wrow0 + (size_t)16 * 4608;

    f32x4 acc[8];
    f32x4 zf = {0.f, 0.f, 0.f, 0.f};
#pragma unroll
    for (int i = 0; i < 8; ++i) acc[i] = zf;

    int niter = 9 * cper;   // 18 / 36 / 72, always even
    Frag F0, F1;
    k1_load(F0, 0, cperm1, cperLog, chb, quad, prow[0], prow[1], prow[2], prow[3],
            wrow0, wrow1, xthi, xtlo, whi, wlo);
    for (int it = 0; it < niter; it += 2) {
        k1_load(F1, it + 1, cperm1, cperLog, chb, quad, prow[0], prow[1], prow[2], prow[3],
                wrow0, wrow1, xthi, xtlo, whi, wlo);
        k1_step(F0, acc);
        if (it + 2 < niter)
            k1_load(F0, it + 2, cperm1, cperLog, chb, quad, prow[0], prow[1], prow[2], prow[3],
                    wrow0, wrow1, xthi, xtlo, whi, wlo);
        k1_step(F1, acc);
    }
    // C/D: col(px)=lane&15, row(oc)=quad*4+reg
#pragma unroll
    for (int so = 0; so < 2; ++so)
#pragma unroll
        for (int sp = 0; sp < 4; ++sp)
#pragma unroll
            for (int r = 0; r < 4; ++r) {
                int oc = ocbase + so * 16 + quad * 4 + r;
                int px = pxbase + sp * 16 + m;
                pk[((size_t)bs * 512 + oc) * 2560 + px] = acc[so * 4 + sp][r];
            }
}

// ---------------------------------------------------------------------------
// K2a: fused k-split reduce + bias + ReLU + 1x1 heads partial GEMM.
// Grid (40 px-tiles, 8 c-chunks) = 320 blocks (full parallelism — the R4
// 40-block fusion collapsed occupancy to 1.9% and cost 324 us).
// Each block: v[c][px] = relu(br + sum_ks pk) staged in LDS, then 45x64 MAC.
// ---------------------------------------------------------------------------
__global__ __launch_bounds__(256) void k2a_heads(const float* __restrict__ pk, int ns,
                                                 const float* __restrict__ br,
                                                 const float* __restrict__ wcls,
                                                 const float* __restrict__ wreg,
                                                 float* __restrict__ part)
{
    __shared__ float vt[64 * 64];
    __shared__ float Wl[45 * 64];
    int t  = threadIdx.x;
    int pb = blockIdx.x;           // 0..39
    int s  = blockIdx.y;           // 0..7
    int cb = s * 64;
    for (int e = t; e < 45 * 64; e += 256) {
        int u = e >> 6, c = e & 63;
        Wl[e] = (u < 9) ? wcls[u * 512 + cb + c] : wreg[(u - 9) * 512 + cb + c];
    }
    int pxl = t & 63, ug = t >> 6;
    int px = pb * 64 + pxl;
    bool ok = px < NPX;
#pragma unroll
    for (int i = 0; i < 16; ++i) {
        int c = ug * 16 + i;       // wave-uniform
        float v = 0.f;
        if (ok) {
            size_t bidx = (size_t)(cb + c) * 2560 + px;
            v = br[cb + c];
            for (int ks = 0; ks < ns; ++ks) v += pk[(size_t)ks * 512 * 2560 + bidx];
            v = v > 0.f ? v : 0.f;
        }
        vt[c * 64 + pxl] = v;
    }
    __syncthreads();
    int ubase = ug * 12;
    int ulim  = (45 - ubase < 12) ? (45 - ubase) : 12;
    float acc[12];
#pragma unroll
    for (int j = 0; j < 12; ++j) acc[j] = 0.f;
    for (int c = 0; c < 64; ++c) {
        float v = vt[c * 64 + pxl];
#pragma unroll
        for (int j = 0; j < 12; ++j)
            acc[j] = fmaf(v, Wl[(ubase + j) * 64 + c], acc[j]);
    }
    if (ok) {
        for (int j = 0; j < ulim; ++j)
            part[((size_t)s * 45 + ubase + j) * NPX + px] = acc[j];
    }
}

// ---------------------------------------------------------------------------
// K2b: reduce partials + bias, sigmoid, decode, clip, validity, sort key.
// ---------------------------------------------------------------------------
__global__ __launch_bounds__(256) void k2b_decode(const float* __restrict__ part,
                                                  const float* __restrict__ bcls,
                                                  const float* __restrict__ breg,
                                                  AnchorBase ab,
                                                  float* __restrict__ score,
                                                  float* __restrict__ bx1, float* __restrict__ by1,
                                                  float* __restrict__ bx2, float* __restrict__ by2,
                                                  u32* __restrict__ valid,
                                                  u64* __restrict__ key)
{
    int id = blockIdx.x * 256 + threadIdx.x;
    if (id >= NANCH) return;
    int k  = id / NPX;
    int px = id - k * NPX;

    float z  = bcls[k];
    float d0 = breg[k * 4 + 0], d1 = breg[k * 4 + 1];
    float d2 = breg[k * 4 + 2], d3 = breg[k * 4 + 3];
#pragma unroll
    for (int s = 0; s < 8; ++s) {
        const float* p = part + (size_t)s * 45 * NPX;
        z  += p[(size_t)k * NPX + px];
        d0 += p[(size_t)(9 + k * 4 + 0) * NPX + px];
        d1 += p[(size_t)(9 + k * 4 + 1) * NPX + px];
        d2 += p[(size_t)(9 + k * 4 + 2) * NPX + px];
        d3 += p[(size_t)(9 + k * 4 + 3) * NPX + px];
    }
    float sc = 1.f / (1.f + expf(-z));

    int yy = px / 50, xx = px - (px / 50) * 50;
    float fx = (float)xx, fy = (float)yy;
    float ax1 = fx + ab.b[k * 4 + 0], ay1 = fy + ab.b[k * 4 + 1];
    float ax2 = fx + ab.b[k * 4 + 2], ay2 = fy + ab.b[k * 4 + 3];
    float aw = ax2 - ax1, ah = ay2 - ay1;
    float cx = ax1 + 0.5f * aw, cy = ay1 + 0.5f * ah;
    float pcx = d0 * aw + cx, pcy = d1 * ah + cy;
    float pw = expf(d2) * aw, ph = expf(d3) * ah;
    float x1 = pcx - 0.5f * pw, y1 = pcy - 0.5f * ph;
    float x2 = pcx + 0.5f * pw, y2 = pcy + 0.5f * ph;
    x1 = fminf(fmaxf(x1, 0.f), 800.f);
    y1 = fminf(fmaxf(y1, 0.f), 800.f);
    x2 = fminf(fmaxf(x2, 0.f), 800.f);
    y2 = fminf(fmaxf(y2, 0.f), 800.f);
    u32 v = ((x2 - x1) >= 16.f) && ((y2 - y1) >= 16.f);

    int f = px * 9 + k;
    score[f] = sc;
    bx1[f] = x1; by1[f] = y1; bx2[f] = x2; by2[f] = y2;
    valid[f] = v;
    u32 sb = __float_as_uint(sc);
    key[f] = ((u64)(~sb) << 32) | (u32)f;
}

// ---------------------------------------------------------------------------
// K3a: partial ranks (deterministic, no atomics).
// ---------------------------------------------------------------------------
__global__ __launch_bounds__(256) void k3a_rank(const u64* __restrict__ key,
                                                u32* __restrict__ rankp)
{
    __shared__ u64 sk[4500];
    int t  = threadIdx.x;
    int jb = blockIdx.y;
    for (int e = t; e < 4500; e += 256) sk[e] = key[jb * 4500 + e];
    __syncthreads();
    int i = blockIdx.x * 256 + t;
    if (i >= NANCH) return;
    u64 ki = key[i];
    u32 cnt = 0;
#pragma unroll 8
    for (int j = 0; j < 4500; ++j) cnt += (sk[j] < ki) ? 1u : 0u;
    rankp[(size_t)jb * NANCH + i] = cnt;
}

// ---------------------------------------------------------------------------
// K3b: sum partial ranks, scatter top-10000; sInv[r] = 1 if invalid box.
// ---------------------------------------------------------------------------
__global__ __launch_bounds__(256) void k3b_gather(const u32* __restrict__ rankp,
                                                  const float* __restrict__ score,
                                                  const float* __restrict__ bx1, const float* __restrict__ by1,
                                                  const float* __restrict__ bx2, const float* __restrict__ by2,
                                                  const u32* __restrict__ valid,
                                                  float* __restrict__ sS,
                                                  float* __restrict__ sx1, float* __restrict__ sy1,
                                                  float* __restrict__ sx2, float* __restrict__ sy2,
                                                  float* __restrict__ sA,
                                                  u32* __restrict__ sInv)
{
    int i = blockIdx.x * 256 + threadIdx.x;
    if (i >= NANCH) return;
    u32 r = rankp[i] + rankp[NANCH + i] + rankp[2 * NANCH + i]
          + rankp[3 * NANCH + i] + rankp[4 * NANCH + i];
    if (r >= PRE_TOPK) return;
    float x1 = bx1[i], y1 = by1[i], x2 = bx2[i], y2 = by2[i];
    sS[r] = score[i];
    sx1[r] = x1; sy1[r] = y1; sx2[r] = x2; sy2[r] = y2;
    sA[r] = (x2 - x1) * (y2 - y1);
    sInv[r] = valid[i] ? 0u : 1u;
}

// ---------------------------------------------------------------------------
// K4: pairwise suppression matrix + selfw[i] = rows[i][i>>6].
// ---------------------------------------------------------------------------
__global__ __launch_bounds__(256) void k4_mat(const float* __restrict__ sx1, const float* __restrict__ sy1,
                                              const float* __restrict__ sx2, const float* __restrict__ sy2,
                                              const float* __restrict__ sA,
                                              u64* __restrict__ rows,
                                              u64* __restrict__ selfw)
{
    __shared__ float jx1[1024], jy1[1024], jx2[1024], jy2[1024], ja[1024];
    int t  = threadIdx.x;
    int ib = blockIdx.x;
    int jc = blockIdx.y;
    for (int e = t; e < 1024; e += 256) {
        int j = jc * 1024 + e;
        bool okj = j < PRE_TOPK;
        jx1[e] = okj ? sx1[j] : 0.f;
        jy1[e] = okj ? sy1[j] : 0.f;
        jx2[e] = okj ? sx2[j] : 0.f;
        jy2[e] = okj ? sy2[j] : 0.f;
        ja[e]  = okj ? sA[j]  : 0.f;
    }
    __syncthreads();
    int i = ib * 256 + t;
    if (i >= PRE_TOPK) return;
    u64* rowp = rows + (size_t)i * NWORDS + jc * 16;
    if (jc * 1024 + 1023 <= i) {
#pragma unroll
        for (int w = 0; w < 16; ++w) rowp[w] = 0ull;
        int sw_ = i >> 6;
        if (sw_ >= jc * 16 && sw_ < jc * 16 + 16) selfw[i] = 0ull;
        return;
    }
    float x1 = sx1[i], y1 = sy1[i], x2 = sx2[i], y2 = sy2[i], ai = sA[i];
    u64 word = 0;
#pragma unroll 4
    for (int e = 0; e < 1024; ++e) {
        int j = jc * 1024 + e;
        float xx1 = fmaxf(x1, jx1[e]);
        float yy1 = fmaxf(y1, jy1[e]);
        float xx2 = fminf(x2, jx2[e]);
        float yy2 = fminf(y2, jy2[e]);
        float iw = fmaxf(xx2 - xx1, 0.f);
        float ih = fmaxf(yy2 - yy1, 0.f);
        float inter = iw * ih;
        float uni = ai + ja[e] - inter;
        bool sup = (inter > 0.7f * uni) && (j > i) && (j < PRE_TOPK);
        word |= ((u64)sup) << (e & 63);
        if ((e & 63) == 63) {
            rowp[e >> 6] = word;
            if ((jc * 16 + (e >> 6)) == (i >> 6)) selfw[i] = word;
            word = 0;
        }
    }
}

// ---------------------------------------------------------------------------
// K5: word-batched greedy NMS scan (batch 16); initial removed bits from sInv;
// zero-fills output tail.
// ---------------------------------------------------------------------------
__global__ __launch_bounds__(64) void k5_scan(const u64* __restrict__ rows,
                                              const u64* __restrict__ selfw,
                                              const u32* __restrict__ sInv,
                                              const float* __restrict__ sS,
                                              const float* __restrict__ sx1, const float* __restrict__ sy1,
                                              const float* __restrict__ sx2, const float* __restrict__ sy2,
                                              float* __restrict__ out)
{
    __shared__ int keptList[2000];
    __shared__ int kcnt;
    int l = threadIdx.x;
    auto bw = [&](int w) -> u64 {
        const uint4* p = (const uint4*)(sInv + (size_t)w * 64);
        u64 v = 0;
#pragma unroll
        for (int j = 0; j < 16; ++j) {
            uint4 q = p[j];
            v |= ((u64)(q.x != 0) << (j * 4))     | ((u64)(q.y != 0) << (j * 4 + 1))
               | ((u64)(q.z != 0) << (j * 4 + 2)) | ((u64)(q.w != 0) << (j * 4 + 3));
        }
        return v;
    };
    u64 r0 = bw(l);
    u64 r1 = bw(64 + l);
    u64 r2 = (l < 32) ? bw(128 + l) : ~0ull;
    u64 swreg = selfw[l];
    int cnt = 0;
    bool done = false;
    for (int w = 0; w < 157 && !done; ++w) {
        u64 swnext = (w < 156) ? selfw[(size_t)(w + 1) * 64 + l] : 0ull;
        int slot = w >> 6, owner = w & 63;
        u64 val = (slot == 0) ? r0 : (slot == 1) ? r1 : r2;
        u64 rw = __shfl(val, owner, 64);
        u64 wmask = (w == 156) ? 0xFFFFull : ~0ull;
        u64 av = (~rw) & wmask;
        u64 km = 0;
        while (av) {                     // intra-word resolve, registers only
            int b = __ffsll((unsigned long long)av) - 1;
            u64 sw = __shfl(swreg, b, 64);
            km |= 1ull << b;
            av &= ~(1ull << b);
            av &= ~sw;
        }
        u64 kk = km;
        while (kk) {                     // OR kept rows, 16 per batch
            int bsx[16];
            int nb = 0;
            while (kk && nb < 16) {
                int b = __ffsll((unsigned long long)kk) - 1;
                kk &= kk - 1;
                bsx[nb++] = b;
            }
            u64 a0 = 0, a1 = 0, a2 = 0;
#pragma unroll
            for (int u = 0; u < 16; ++u) {
                if (u < nb) {
                    int i = (w << 6) + bsx[u];
                    if (l == 0 && cnt + u < 2000) keptList[cnt + u] = i;
                    const u64* rp = rows + (size_t)i * NWORDS;
                    a0 |= rp[l];
                    a1 |= rp[64 + l];
                    if (l < 32) a2 |= rp[128 + l];
                }
            }
            r0 |= a0; r1 |= a1; r2 |= a2;
            cnt += nb;
            if (cnt >= 2000) { done = true; break; }
        }
        swreg = swnext;
    }
    if (l == 0) kcnt = (cnt < 2000) ? cnt : 2000;
    __syncthreads();
    int K = kcnt;
    for (int r = l; r < 2000; r += 64) {
        if (r < K) {
            int j = keptList[r];
            out[r * 4 + 0] = sx1[j];
            out[r * 4 + 1] = sy1[j];
            out[r * 4 + 2] = sx2[j];
            out[r * 4 + 3] = sy2[j];
            out[8000 + r]  = sS[j];
        } else {
            out[r * 4 + 0] = 0.f; out[r * 4 + 1] = 0.f;
            out[r * 4 + 2] = 0.f; out[r * 4 + 3] = 0.f;
            out[8000 + r]  = 0.f;
        }
    }
}

// ---------------------------------------------------------------------------
extern "C" void kernel_launch(void* const* d_in, const int* in_sizes, int n_in,
                              void* d_out, int out_size, void* d_ws, size_t ws_size,
                              hipStream_t stream)
{
    (void)in_sizes; (void)n_in; (void)out_size;
    const float* feat = (const float*)d_in[1];
    const float* wrpn = (const float*)d_in[3];
    const float* brpn = (const float*)d_in[4];
    const float* wcls = (const float*)d_in[5];
    const float* bcls = (const float*)d_in[6];
    const float* wreg = (const float*)d_in[7];
    const float* breg = (const float*)d_in[8];
    float* out = (float*)d_out;

    // K-split factor by workspace budget. need(ns) = ns*512*2560*4 + 16,252,928.
    // (R4 confirmed ns=4 branch runs: FETCH(k2)=20.65MB ~= 21MB pk.)
    int ns = (ws_size >= 58195968) ? 8 : (ws_size >= 37224448) ? 4 : 2;
    int cper = 16 / ns;
    int cperLog = (ns == 2) ? 3 : (ns == 4) ? 2 : 1;
    size_t pkB = (size_t)ns * 512 * 2560 * 4;

    char* ws = (char*)d_ws;
    // Live ranges:
    //   [0,pkB)           pk      k1m..k2a ; then rows (k4..k5) at [0,12.8M)
    //   [pkB,pkB+16.25M)  Xt+W    kprep..k1m ; then smalls+part (k2a+)
    float* pk = (float*)ws;
    u64*   rows = (u64*)ws;                      // 12,800,000 (after pk dies)
    unsigned short* Xthi = (unsigned short*)(ws + pkB);
    unsigned short* Xtlo = Xthi + (size_t)52 * 64 * 512;
    unsigned short* Whi  = (unsigned short*)(ws + pkB + 6815744);
    unsigned short* Wlo  = Whi + (size_t)512 * 4608;

    char* sm = ws + pkB;                         // overlays Xt/W (dead after k1m)
    float* score = (float*)(sm + 0);             // 90,000
    float* bx1   = (float*)(sm + 90000);
    float* by1   = (float*)(sm + 180000);
    float* bx2   = (float*)(sm + 270000);
    float* by2   = (float*)(sm + 360000);
    u32*   valid = (u32*)  (sm + 450000);
    u64*   key   = (u64*)  (sm + 540000);        // 180,000
    u32*   rankp = (u32*)  (sm + 720000);        // 450,000
    float* sS    = (float*)(sm + 1170000);
    float* sx1   = (float*)(sm + 1210000);
    float* sy1   = (float*)(sm + 1250000);
    float* sx2   = (float*)(sm + 1290000);
    float* sy2   = (float*)(sm + 1330000);
    float* sA    = (float*)(sm + 1370000);
    u32*   sInv  = (u32*)  (sm + 1410000);       // 40,960
    u64*   selfw = (u64*)  (sm + 1450960);       // 81,920
    float* part  = (float*)(sm + 1532880);       // 3,600,000 -> ends sm+5.13M < 16.25M
    // peak footprint = pkB + 16,252,928 (ns=4 -> 37.2 MB, proven available)

    AnchorBase ab;
    {
        const float scales[3] = {128.f, 256.f, 512.f};
        const float aspect[3] = {0.5f, 1.f, 2.f};
        for (int ai = 0; ai < 3; ++ai) {
            float hr = sqrtf(aspect[ai]);
            float wratio = 1.0f / hr;
            for (int si = 0; si < 3; ++si) {
                float wsz = wratio * scales[si];
                float hsz = hr * scales[si];
                int a = ai * 3 + si;
                ab.b[a * 4 + 0] = rintf(-wsz / 2.0f);
                ab.b[a * 4 + 1] = rintf(-hsz / 2.0f);
                ab.b[a * 4 + 2] = rintf( wsz / 2.0f);
                ab.b[a * 4 + 3] = rintf( hsz / 2.0f);
            }
        }
    }

    kprep    <<<928, 256, 0, stream>>>(feat, wrpn, Xthi, Xtlo, Whi, Wlo);
    k1m      <<<dim3(20, 8, ns), 256, 0, stream>>>(Xthi, Xtlo, Whi, Wlo, pk, cper, cperLog);
    k2a_heads<<<dim3(40, 8), 256, 0, stream>>>(pk, ns, brpn, wcls, wreg, part);
    k2b_decode<<<88, 256, 0, stream>>>(part, bcls, breg, ab, score, bx1, by1, bx2, by2, valid, key);
    k3a_rank <<<dim3(88, 5), 256, 0, stream>>>(key, rankp);
    k3b_gather<<<88, 256, 0, stream>>>(rankp, score, bx1, by1, bx2, by2, valid,
                                       sS, sx1, sy1, sx2, sy2, sA, sInv);
    k4_mat   <<<dim3(40, 10), 256, 0, stream>>>(sx1, sy1, sx2, sy2, sA, rows, selfw);
    k5_scan  <<<1, 64, 0, stream>>>(rows, selfw, sInv, sS, sx1, sy1, sx2, sy2, out);
}